// Round 2
// baseline (20499.409 us; speedup 1.0000x reference)
//
#include <hip/hip_runtime.h>

typedef __bf16 bf16_t;
typedef __bf16 bf16x8 __attribute__((ext_vector_type(8)));
typedef float f32x4 __attribute__((ext_vector_type(4)));

constexpr int kB = 64, kT = 256, kE = 128, kH = 1024, kV = 16384;
constexpr int kBT = kB * kT;

// ---------------- zero a byte range (multiple of 16) ----------------
__global__ void zero_bytes(char* p, size_t n) {
    size_t stride = (size_t)gridDim.x * blockDim.x * 16;
    for (size_t i = ((size_t)blockIdx.x * blockDim.x + threadIdx.x) * 16; i < n; i += stride) {
        uint4 z; z.x = z.y = z.z = z.w = 0;
        *reinterpret_cast<uint4*>(p + i) = z;
    }
}

// ---------------- transpose fp32 [R][C] -> bf16 [C][R] ----------------
__global__ void transpose_to_bf16(const float* __restrict__ src, bf16_t* __restrict__ dst,
                                  int R, int C) {
    __shared__ float tile[32][33];
    int c0 = blockIdx.x * 32, r0 = blockIdx.y * 32;
    for (int rr = threadIdx.y; rr < 32; rr += 8)
        tile[rr][threadIdx.x] = src[(size_t)(r0 + rr) * C + c0 + threadIdx.x];
    __syncthreads();
    for (int rr = threadIdx.y; rr < 32; rr += 8)
        dst[(size_t)(c0 + rr) * R + r0 + threadIdx.x] = (bf16_t)tile[threadIdx.x][rr];
}

// ---------------- embedding gather to bf16 [kBT][128] ----------------
__global__ __launch_bounds__(256) void embed_gather(const int* __restrict__ ids,
                                                    const float* __restrict__ emb,
                                                    bf16_t* __restrict__ XB) {
    int base = blockIdx.x * 16;
    for (int idx = threadIdx.x; idx < 16 * kE; idx += 256) {
        int r = idx >> 7, k = idx & 127;
        int row = base + r;
        XB[(size_t)row * kE + k] = (bf16_t)emb[(size_t)ids[row] * kE + k];
    }
}

// ---------------- x-precompute GEMM: C[M][N] = bias + XB[M][128] @ WT[N][128]^T ----
__global__ __launch_bounds__(256) void xpre_gemm(
    const bf16_t* __restrict__ XB, const bf16_t* __restrict__ WT,
    const float* __restrict__ bias, float* __restrict__ Cout, int N) {
    __shared__ __align__(16) char As[128 * 256];
    __shared__ __align__(16) char Bs[128 * 256];
    const int tid = threadIdx.x;
    const int w = tid >> 6, l = tid & 63, lr = l & 15, lk8 = (l >> 4) * 8;
    const int wr = w >> 1, wc = w & 1;
    const size_t row0 = (size_t)blockIdx.y * 128, col0 = (size_t)blockIdx.x * 128;
    for (int c = tid; c < 2048; c += 256) {
        int o = c * 16; int row = o >> 8; int kk = o & 255;
        int dst = (row << 8) + (kk ^ ((row & 7) << 4));
        *reinterpret_cast<bf16x8*>(As + dst) =
            *reinterpret_cast<const bf16x8*>(XB + (row0 + row) * kE + (kk >> 1));
        *reinterpret_cast<bf16x8*>(Bs + dst) =
            *reinterpret_cast<const bf16x8*>(WT + (col0 + row) * kE + (kk >> 1));
    }
    __syncthreads();
    f32x4 acc[4][4] = {};
    #pragma unroll
    for (int ks = 0; ks < 4; ++ks) {
        int kb = (ks * 32 + lk8) * 2;
        bf16x8 af[4], bfv[4];
        #pragma unroll
        for (int mf = 0; mf < 4; ++mf) {
            int r = wr * 64 + mf * 16 + lr;
            af[mf] = *reinterpret_cast<const bf16x8*>(As + (r << 8) + (kb ^ ((r & 7) << 4)));
        }
        #pragma unroll
        for (int nf = 0; nf < 4; ++nf) {
            int r = wc * 64 + nf * 16 + lr;
            bfv[nf] = *reinterpret_cast<const bf16x8*>(Bs + (r << 8) + (kb ^ ((r & 7) << 4)));
        }
        #pragma unroll
        for (int mf = 0; mf < 4; ++mf)
            #pragma unroll
            for (int nf = 0; nf < 4; ++nf)
                acc[mf][nf] = __builtin_amdgcn_mfma_f32_16x16x32_bf16(af[mf], bfv[nf], acc[mf][nf], 0, 0, 0);
    }
    #pragma unroll
    for (int mf = 0; mf < 4; ++mf) {
        size_t row = row0 + wr * 64 + mf * 16 + (l >> 4) * 4;
        #pragma unroll
        for (int nf = 0; nf < 4; ++nf) {
            size_t col = col0 + wc * 64 + nf * 16 + lr;
            float bvl = bias[col];
            #pragma unroll
            for (int i = 0; i < 4; ++i)
                Cout[(row + i) * (size_t)N + col] = acc[mf][nf][i] + bvl;
        }
    }
}

// ---------------- persistent RNN ----------------
struct PP {
    const bf16_t *WG1HT, *WC1HT, *WG2T, *WC2T;  // [N][K] bf16
    const float *XG1, *XC1;                     // [kBT][2048]/[1024] fp32
    const float *bg2, *bc2;
    float *H1F, *H2F, *U1, *U2;
    bf16_t *X2, *X2C0, *X2C1, *RH1, *YS;
    unsigned *cnt;                              // padded: c1=cnt[0],c2=cnt[32],c3=cnt[64],c4=cnt[96]
};

__device__ __forceinline__ void wait_ge(unsigned* p, unsigned tgt) {
    while (__hip_atomic_load(p, __ATOMIC_ACQUIRE, __HIP_MEMORY_SCOPE_AGENT) < tgt)
        __builtin_amdgcn_s_sleep(1);
}

template<int K>
__device__ __forceinline__ void mm_phase(const bf16_t* __restrict__ A, int astr,
                                         const char* __restrict__ wl,
                                         int w, int lr, int lk, f32x4 (&acc)[4][2]) {
    constexpr int RBSH = (K == 1024) ? 11 : 12;   // row bytes = K*2 = 1<<RBSH
    const int kbeg = w * (K / 4);
    #pragma unroll 4
    for (int ki = 0; ki < K / 128; ++ki) {
        int k0 = kbeg + ki * 32;
        bf16x8 av[4];
        #pragma unroll
        for (int mf = 0; mf < 4; ++mf)
            av[mf] = *reinterpret_cast<const bf16x8*>(A + (size_t)(mf * 16 + lr) * astr + k0 + lk);
        #pragma unroll
        for (int nf = 0; nf < 2; ++nf) {
            int r = nf * 16 + lr;
            int kb = (k0 + lk) * 2;
            bf16x8 wv = *reinterpret_cast<const bf16x8*>(wl + (r << RBSH) + (kb ^ ((r & 7) << 4)));
            #pragma unroll
            for (int mf = 0; mf < 4; ++mf)
                acc[mf][nf] = __builtin_amdgcn_mfma_f32_16x16x32_bf16(av[mf], wv, acc[mf][nf], 0, 0, 0);
        }
    }
}

// 192 blocks: [0,64)=gates1, [64,96)=cand1, [96,160)=gates2, [160,192)=cand2.
// Weights staged in LDS once (XOR-swizzled); per-step sync via monotonic counters.
// Hazard audit (readers must finish before writers overwrite):
//   P1(t) waits c2>=32t            (h1(t-1), H1F, RH1/U1 free after P2(t-1))
//   P2(t) waits c1>=64(t+1), c3>=64t (X2 h1-half free after P3(t-1)),
//         c4>=32(t-1) for t>=2     (X2C[t&1] h1-half free after P4(t-2))
//   P3(t) waits c2>=32(t+1), c4>=32t (h2(t-1); X2C[t&1] rh2-half & U2 free)
//   P4(t) waits c3>=64(t+1)
__global__ __launch_bounds__(256, 1) void rnn_persistent(PP P) {
    __shared__ __align__(16) char wlds[131072];
    __shared__ float red[4][64][8];
    const int blk = blockIdx.x, tid = threadIdx.x;
    const int w = tid >> 6, l = tid & 63, lr = l & 15, lk = (l >> 4) * 8;
    int grp, idx;
    if (blk < 64)       { grp = 0; idx = blk; }
    else if (blk < 96)  { grp = 1; idx = blk - 64; }
    else if (blk < 160) { grp = 2; idx = blk - 96; }
    else                { grp = 3; idx = blk - 160; }
    const int n0 = idx * 32;
    const int K = (grp < 2) ? 1024 : 2048;
    const int rbsh = (grp < 2) ? 11 : 12;
    const bf16_t* Wsrc = (grp == 0) ? P.WG1HT : (grp == 1) ? P.WC1HT : (grp == 2) ? P.WG2T : P.WC2T;

    // stage weight slice rows [n0, n0+32) into LDS, XOR-swizzled within each row
    for (int c = tid; c < (32 * K * 2) / 16; c += 256) {
        int o = c * 16;
        int row = o >> rbsh;
        int kk = o & ((1 << rbsh) - 1);
        bf16x8 v = *reinterpret_cast<const bf16x8*>(Wsrc + (size_t)(n0 + row) * K + (kk >> 1));
        *reinterpret_cast<bf16x8*>(wlds + (row << rbsh) + (kk ^ ((row & 7) << 4))) = v;
    }
    __syncthreads();

    unsigned* c1 = P.cnt;
    unsigned* c2 = P.cnt + 32;
    unsigned* c3 = P.cnt + 64;
    unsigned* c4 = P.cnt + 96;

    for (int t = 0; t < kT; ++t) {
        if (tid == 0) {
            unsigned ut = (unsigned)t;
            if (grp == 0) {
                if (t) wait_ge(c2, 32u * ut);
            } else if (grp == 1) {
                wait_ge(c1, 64u * (ut + 1));
                if (t) wait_ge(c3, 64u * ut);
                if (t >= 2) wait_ge(c4, 32u * (ut - 1));
            } else if (grp == 2) {
                wait_ge(c2, 32u * (ut + 1));
                if (t) wait_ge(c4, 32u * ut);
            } else {
                wait_ge(c3, 64u * (ut + 1));
            }
        }
        __syncthreads();

        bf16_t* x2c = (t & 1) ? P.X2C1 : P.X2C0;
        f32x4 acc[4][2] = {};
        if (grp == 0)      mm_phase<1024>(P.X2, 2048, wlds, w, lr, lk, acc);
        else if (grp == 1) mm_phase<1024>(P.RH1, 1024, wlds, w, lr, lk, acc);
        else if (grp == 2) mm_phase<2048>(P.X2, 2048, wlds, w, lr, lk, acc);
        else               mm_phase<2048>(x2c, 2048, wlds, w, lr, lk, acc);

        // cross-wave reduce + epilogue, 4 passes of 8 cols (red = 8 KB)
        #pragma unroll
        for (int p = 0; p < 4; ++p) {
            const int nf = p >> 1;
            if (((l >> 3) & 1) == (p & 1)) {
                #pragma unroll
                for (int mf = 0; mf < 4; ++mf)
                    #pragma unroll
                    for (int i = 0; i < 4; ++i)
                        red[w][mf * 16 + (l >> 4) * 4 + i][l & 7] = acc[mf][nf][i];
            }
            __syncthreads();
            {
                int r = tid >> 2;                 // batch row 0..63
                int cbase = (tid & 3) * 2;
                #pragma unroll
                for (int e = 0; e < 2; ++e) {
                    int c = cbase + e;
                    float v = red[0][r][c] + red[1][r][c] + red[2][r][c] + red[3][r][c];
                    int j = n0 + p * 8 + c;
                    if (grp == 0) {
                        v += P.XG1[((size_t)r * kT + t) * 2048 + j];
                        float g = 1.f / (1.f + __expf(-v));
                        if (j < 1024) P.RH1[r * 1024 + j] = (bf16_t)(g * P.H1F[r * 1024 + j]);
                        else          P.U1[r * 1024 + j - 1024] = g;
                    } else if (grp == 1) {
                        v += P.XC1[((size_t)r * kT + t) * 1024 + j];
                        float cc = tanhf(v);
                        float u = P.U1[r * 1024 + j], ho = P.H1F[r * 1024 + j];
                        float hn = u * ho + (1.f - u) * cc;
                        P.H1F[r * 1024 + j] = hn;
                        bf16_t hb = (bf16_t)hn;
                        P.X2[r * 2048 + j] = hb;
                        x2c[r * 2048 + j] = hb;
                    } else if (grp == 2) {
                        v += P.bg2[j];
                        float g = 1.f / (1.f + __expf(-v));
                        if (j < 1024) x2c[r * 2048 + 1024 + j] = (bf16_t)(g * P.H2F[r * 1024 + j]);
                        else          P.U2[r * 1024 + j - 1024] = g;
                    } else {
                        v += P.bc2[j];
                        float cc = tanhf(v);
                        float u = P.U2[r * 1024 + j], ho = P.H2F[r * 1024 + j];
                        float hn = u * ho + (1.f - u) * cc;
                        P.H2F[r * 1024 + j] = hn;
                        bf16_t hb = (bf16_t)hn;
                        P.X2[r * 2048 + 1024 + j] = hb;
                        P.YS[((size_t)r * kT + t) * 1024 + j] = hb;
                    }
                }
            }
            __syncthreads();
        }

        if (tid == 0) {
            __threadfence();   // release all this block's stores device-wide
            if (grp == 0)      atomicAdd(c1, 1u);
            else if (grp == 1) atomicAdd(c2, 1u);
            else if (grp == 2) atomicAdd(c3, 1u);
            else               atomicAdd(c4, 1u);
        }
    }
}

// ---------------- logits GEMM: [16384,1024]bf16 @ [1024,16384] (Bt pre-transposed) ----
__global__ __launch_bounds__(256) void logits_gemm(
    const bf16_t* __restrict__ Amat,   // [kBT][kH]
    const bf16_t* __restrict__ Bt,     // [kV][kH]
    const float* __restrict__ bias,    // [kV]
    float* __restrict__ out) {         // [kBT][kV]
    __shared__ __align__(16) bf16_t As[128 * 64];
    __shared__ __align__(16) bf16_t Bs[128 * 64];
    const int tid = threadIdx.x;
    const int w = tid >> 6, l = tid & 63;
    const int wr = w >> 1, wc = w & 1;
    const int lr = l & 15, lk8 = (l >> 4) * 8;
    const int row0 = blockIdx.y * 128, col0 = blockIdx.x * 128;

    int srow[4], scol[4];
    #pragma unroll
    for (int v = 0; v < 4; ++v) {
        int idx = v * 256 + tid;
        srow[v] = idx >> 3;
        scol[v] = (idx & 7) * 8;
    }

    f32x4 acc[4][4] = {};
    bf16x8 ra[4], rb[4];
    #pragma unroll
    for (int v = 0; v < 4; ++v) {
        ra[v] = *reinterpret_cast<const bf16x8*>(Amat + (size_t)(row0 + srow[v]) * kH + scol[v]);
        rb[v] = *reinterpret_cast<const bf16x8*>(Bt + (size_t)(col0 + srow[v]) * kH + scol[v]);
    }
    for (int kt = 0; kt < 16; ++kt) {
        __syncthreads();
        #pragma unroll
        for (int v = 0; v < 4; ++v) {
            *reinterpret_cast<bf16x8*>(As + srow[v] * 64 + scol[v]) = ra[v];
            *reinterpret_cast<bf16x8*>(Bs + srow[v] * 64 + scol[v]) = rb[v];
        }
        __syncthreads();
        if (kt < 15) {
            int ko = (kt + 1) * 64;
            #pragma unroll
            for (int v = 0; v < 4; ++v) {
                ra[v] = *reinterpret_cast<const bf16x8*>(Amat + (size_t)(row0 + srow[v]) * kH + ko + scol[v]);
                rb[v] = *reinterpret_cast<const bf16x8*>(Bt + (size_t)(col0 + srow[v]) * kH + ko + scol[v]);
            }
        }
        #pragma unroll
        for (int ks = 0; ks < 2; ++ks) {
            bf16x8 af[4], bfv[4];
            #pragma unroll
            for (int mf = 0; mf < 4; ++mf)
                af[mf] = *reinterpret_cast<const bf16x8*>(As + (wr * 64 + mf * 16 + lr) * 64 + ks * 32 + lk8);
            #pragma unroll
            for (int nf = 0; nf < 4; ++nf)
                bfv[nf] = *reinterpret_cast<const bf16x8*>(Bs + (wc * 64 + nf * 16 + lr) * 64 + ks * 32 + lk8);
            #pragma unroll
            for (int mf = 0; mf < 4; ++mf)
                #pragma unroll
                for (int nf = 0; nf < 4; ++nf)
                    acc[mf][nf] = __builtin_amdgcn_mfma_f32_16x16x32_bf16(af[mf], bfv[nf], acc[mf][nf], 0, 0, 0);
        }
    }
    #pragma unroll
    for (int mf = 0; mf < 4; ++mf) {
        int row = row0 + wr * 64 + mf * 16 + (l >> 4) * 4;
        #pragma unroll
        for (int nf = 0; nf < 4; ++nf) {
            int col = col0 + wc * 64 + nf * 16 + lr;
            float bvl = bias[col];
            #pragma unroll
            for (int i = 0; i < 4; ++i)
                out[(size_t)(row + i) * kV + col] = acc[mf][nf][i] + bvl;
        }
    }
}

// ---------------- online log-softmax NLL per row ----------------
__global__ __launch_bounds__(256) void row_nll(const float* __restrict__ logits,
                                               const int* __restrict__ targets,
                                               float* __restrict__ nll) {
    int row = blockIdx.x;
    const float* rowp = logits + (size_t)row * kV;
    int tid = threadIdx.x;
    float m = -1e30f, s = 0.f;
    for (int j = tid; j < kV; j += 256) {
        float v = rowp[j];
        if (v > m) { s = s * __expf(m - v) + 1.f; m = v; }
        else s += __expf(v - m);
    }
    __shared__ float ms[256], ss[256];
    ms[tid] = m; ss[tid] = s;
    __syncthreads();
    for (int off = 128; off; off >>= 1) {
        if (tid < off) {
            float m2 = ms[tid + off], s2 = ss[tid + off];
            float M = fmaxf(ms[tid], m2);
            ss[tid] = ss[tid] * __expf(ms[tid] - M) + s2 * __expf(m2 - M);
            ms[tid] = M;
        }
        __syncthreads();
    }
    if (tid == 0) {
        float lse = ms[0] + __logf(ss[0]);
        nll[row] = lse - rowp[targets[row]];
    }
}

__global__ __launch_bounds__(256) void loss_reduce(const float* __restrict__ nll,
                                                   float* __restrict__ out) {
    __shared__ float sm[256];
    int tid = threadIdx.x;
    float s = 0.f;
    for (int i = tid; i < kBT; i += 256) s += nll[i];
    sm[tid] = s;
    __syncthreads();
    for (int off = 128; off; off >>= 1) {
        if (tid < off) sm[tid] += sm[tid + off];
        __syncthreads();
    }
    if (tid == 0) out[0] = sm[0] / (float)kBT;
}

// ---------------- host ----------------
extern "C" void kernel_launch(void* const* d_in, const int* in_sizes, int n_in,
                              void* d_out, int out_size, void* d_ws, size_t ws_size,
                              hipStream_t stream) {
    const int*   ids = (const int*)d_in[0];
    const int*   tgt = (const int*)d_in[1];
    const float* emb = (const float*)d_in[2];
    const float* Wg1 = (const float*)d_in[3];
    const float* bg1 = (const float*)d_in[4];
    const float* Wc1 = (const float*)d_in[5];
    const float* bc1 = (const float*)d_in[6];
    const float* Wg2 = (const float*)d_in[7];
    const float* bg2 = (const float*)d_in[8];
    const float* Wc2 = (const float*)d_in[9];
    const float* bc2 = (const float*)d_in[10];
    const float* sw  = (const float*)d_in[11];
    const float* sb  = (const float*)d_in[12];
    float* out = (float*)d_out;

    char* ws = (char*)d_ws;
    size_t off = 0;
    auto alloc = [&](size_t bytes) -> void* {
        void* p = ws + off;
        off += (bytes + 255) & ~(size_t)255;
        return p;
    };
    bf16_t* WG1HT = (bf16_t*)alloc((size_t)2048 * 1024 * 2);
    bf16_t* WC1HT = (bf16_t*)alloc((size_t)1024 * 1024 * 2);
    bf16_t* WG2T  = (bf16_t*)alloc((size_t)2048 * 2048 * 2);
    bf16_t* WC2T  = (bf16_t*)alloc((size_t)1024 * 2048 * 2);
    bf16_t* SWT   = (bf16_t*)alloc((size_t)kV * kH * 2);
    bf16_t* WG1XT = (bf16_t*)alloc((size_t)2048 * kE * 2);
    bf16_t* WC1XT = (bf16_t*)alloc((size_t)1024 * kE * 2);
    bf16_t* XB    = (bf16_t*)alloc((size_t)kBT * kE * 2);
    float*  XG1   = (float*)alloc((size_t)kBT * 2048 * 4);
    float*  XC1   = (float*)alloc((size_t)kBT * 1024 * 4);
    bf16_t* YS    = (bf16_t*)alloc((size_t)kBT * kH * 2);
    float*  NLL   = (float*)alloc((size_t)kBT * 4);
    // ---- contiguous zero region start ----
    char*   zbase = ws + off;
    float*  H1F   = (float*)alloc((size_t)kB * kH * 4);
    float*  H2F   = (float*)alloc((size_t)kB * kH * 4);
    float*  U1    = (float*)alloc((size_t)kB * kH * 4);
    float*  U2    = (float*)alloc((size_t)kB * kH * 4);
    bf16_t* X2    = (bf16_t*)alloc((size_t)kB * 2048 * 2);
    bf16_t* X2C0  = (bf16_t*)alloc((size_t)kB * 2048 * 2);
    bf16_t* X2C1  = (bf16_t*)alloc((size_t)kB * 2048 * 2);
    bf16_t* RH1   = (bf16_t*)alloc((size_t)kB * kH * 2);
    unsigned* CNT = (unsigned*)alloc(128 * 4);
    size_t zlen = (ws + off) - zbase;
    // ---- contiguous zero region end ----

    // weight conversions (bf16, [N][K] layout)
    transpose_to_bf16<<<dim3(64, 32), dim3(32, 8), 0, stream>>>(Wg1 + (size_t)kE * 2048, WG1HT, 1024, 2048);
    transpose_to_bf16<<<dim3(32, 32), dim3(32, 8), 0, stream>>>(Wc1 + (size_t)kE * 1024, WC1HT, 1024, 1024);
    transpose_to_bf16<<<dim3(64, 64), dim3(32, 8), 0, stream>>>(Wg2, WG2T, 2048, 2048);
    transpose_to_bf16<<<dim3(32, 64), dim3(32, 8), 0, stream>>>(Wc2, WC2T, 2048, 1024);
    transpose_to_bf16<<<dim3(512, 32), dim3(32, 8), 0, stream>>>(sw, SWT, 1024, 16384);
    transpose_to_bf16<<<dim3(64, 4), dim3(32, 8), 0, stream>>>(Wg1, WG1XT, 128, 2048);
    transpose_to_bf16<<<dim3(32, 4), dim3(32, 8), 0, stream>>>(Wc1, WC1XT, 128, 1024);

    embed_gather<<<kBT / 16, 256, 0, stream>>>(ids, emb, XB);
    xpre_gemm<<<dim3(16, kBT / 128), 256, 0, stream>>>(XB, WG1XT, bg1, XG1, 2048);
    xpre_gemm<<<dim3(8, kBT / 128), 256, 0, stream>>>(XB, WC1XT, bc1, XC1, 1024);
    zero_bytes<<<256, 256, 0, stream>>>(zbase, zlen);

    PP prm;
    prm.WG1HT = WG1HT; prm.WC1HT = WC1HT; prm.WG2T = WG2T; prm.WC2T = WC2T;
    prm.XG1 = XG1; prm.XC1 = XC1; prm.bg2 = bg2; prm.bc2 = bc2;
    prm.H1F = H1F; prm.H2F = H2F; prm.U1 = U1; prm.U2 = U2;
    prm.X2 = X2; prm.X2C0 = X2C0; prm.X2C1 = X2C1; prm.RH1 = RH1; prm.YS = YS;
    prm.cnt = CNT;
    void* args[] = { &prm };
    hipLaunchCooperativeKernel((const void*)rnn_persistent, dim3(192), dim3(256), args, 0, stream);

    logits_gemm<<<dim3(kV / 128, kBT / 128), 256, 0, stream>>>(YS, SWT, sb, out);
    row_nll<<<kBT, 256, 0, stream>>>(out, tgt, NLL);
    loss_reduce<<<1, 256, 0, stream>>>(NLL, out + (size_t)kBT * kV);
}